// Round 4
// baseline (20.965 us; speedup 1.0000x reference)
//
#include <hip/hip_runtime.h>
#include <hip/hip_fp16.h>

#define B 4
#define CIN 64
#define H 32
#define W 32
#define OC 64
#define LMAX 144
#define HP 34
#define WP 34
#define NPIX 1024
#define RSTR 36                        // padded row stride in f16 elems
#define CSTR (HP*RSTR)                 // 1224 elems per channel
#define GUARD 4                        // zero guard elems (keeps 8B alignment)
#define IMG_ELEMS (GUARD + CIN*CSTR)   // 78,340 elems = 156,680 B

// One block per (b,o), 512 threads, full padded image f16 in LDS.
// R4 changes vs R3: taps read via scalar loads in the gather loop (SGPR,
// bypasses LDS pipe -> 2 LDS instrs/tap instead of 3), and only the pad
// cells are zeroed instead of the whole 157 KB.
// Layout: elem = GUARD + c*CSTR + row*RSTR + (col-1); col-1 underflow for
// kw=0,w=0 lands in the previous row's zeroed col-35 slot (or the guard),
// so the gather is branchless.
__global__ __launch_bounds__(512, 1) void reconv_lds2(
    const float* __restrict__ images,
    const int* __restrict__ tap_idx, const float* __restrict__ tap_w,
    const int* __restrict__ bias_index, const float* __restrict__ bias_value,
    float* __restrict__ out)
{
    __shared__ ushort s_img[IMG_ELEMS];

    const int bo = blockIdx.x;
    const int b = bo >> 6;             // / OC
    const int o = bo & (OC - 1);
    const int t = threadIdx.x;
    const int w = t & 31;
    const int h0 = t >> 5;             // 0..15; thread owns padded rows h0, h0+16

    unsigned long long* s64 = (unsigned long long*)s_img;

    // --- Zero pad cells only (disjoint from staging's interior writes) ---
    if (t == 0) s64[0] = 0ull;         // guard elems 0..3
    // rows 0 and 33, all 36 phys cols: 64ch * 2rows * 9 u64-chunks
    for (int i = t; i < CIN * 2 * 9; i += 512) {
        int c = i / 18;
        int rest = i - c * 18;
        int row = (rest < 9) ? 0 : 33;
        int j = rest % 9;
        int elem = GUARD + c * CSTR + row * RSTR + j * 4;   // elem%4==0
        s64[elem >> 2] = 0ull;
    }
    // phys cols 32..35 of rows 1..32 (right pad + next-row's col -1)
    for (int i = t; i < CIN * 32; i += 512) {
        int c = i >> 5;
        int r = (i & 31) + 1;
        int elem = GUARD + c * CSTR + r * RSTR + 32;        // elem%4==0
        s64[elem >> 2] = 0ull;
    }

    // --- Stage image(b) f32 -> f16 into LDS interior (rows 1..32, cols 0..31) ---
    const float4* img4 = (const float4*)images + (size_t)b * (CIN * H * W / 4);
    #pragma unroll 4
    for (int i = 0; i < 32; ++i) {
        int f = i * 512 + t;
        float4 v = img4[f];
        int c = f >> 8;                // 256 float4 per channel
        int p4 = f & 255;
        int r = p4 >> 3;               // image row 0..31
        int cc = (p4 & 7) << 2;        // image col (mult of 4)
        int e = GUARD + c * CSTR + (r + 1) * RSTR + cc;     // phys col = (cc+1)-1
        ushort4 u;
        u.x = __half_as_ushort(__float2half(v.x));
        u.y = __half_as_ushort(__float2half(v.y));
        u.z = __half_as_ushort(__float2half(v.z));
        u.w = __half_as_ushort(__float2half(v.w));
        *(ushort4*)&s_img[e] = u;      // 8B aligned
    }

    // --- Bias: general scatter-add semantics, uniform scalar work ---
    float bias = 0.f;
    for (int i = 0; i < OC; ++i)
        bias += (bias_index[i] == o) ? bias_value[i] : 0.f;

    __syncthreads();

    // --- Gather: taps via scalar loads, 2 ds_read_u16 per tap ---
    const char* sbase = (const char*)s_img;
    const int pxo = (h0 * RSTR + w) * 2;
    const int* ti = tap_idx + o * LMAX;    // block-uniform -> s_load
    const float* tw = tap_w + o * LMAX;
    float a0 = 0.f, a1 = 0.f;
    #pragma unroll 8
    for (int l = 0; l < LMAX; ++l) {
        int idx = ti[l];
        float wgt = tw[l];
        int c = idx / (HP * WP);           // magic-mul, scalar
        int rem = idx - c * (HP * WP);
        int kh = rem / WP;
        int kw = rem - kh * WP;
        int boff = pxo + (GUARD + c * CSTR + kh * RSTR + kw - 1) * 2;
        float x0 = __half2float(*(const __half*)(sbase + boff));
        float x1 = __half2float(*(const __half*)(sbase + boff + 16 * RSTR * 2));
        a0 = fmaf(wgt, x0, a0);
        a1 = fmaf(wgt, x1, a1);
    }

    float* op = out + (size_t)bo * NPIX;
    op[h0 * 32 + w] = a0 + bias;
    op[(h0 + 16) * 32 + w] = a1 + bias;
}

extern "C" void kernel_launch(void* const* d_in, const int* in_sizes, int n_in,
                              void* d_out, int out_size, void* d_ws, size_t ws_size,
                              hipStream_t stream) {
    const float* images     = (const float*)d_in[0];
    const int*   tap_idx    = (const int*)d_in[1];
    const float* tap_w      = (const float*)d_in[2];
    const int*   bias_index = (const int*)d_in[3];
    const float* bias_value = (const float*)d_in[4];
    float* out = (float*)d_out;

    reconv_lds2<<<B * OC, 512, 0, stream>>>(images, tap_idx, tap_w,
                                            bias_index, bias_value, out);
}

// Round 5
// 15.936 us; speedup vs baseline: 1.3156x; 1.3156x over previous
//
#include <hip/hip_runtime.h>
#include <hip/hip_fp16.h>

#define B 4
#define CIN 64
#define OC 64
#define LMAX 144
#define HP 34
#define WP 34
#define HPW (HP*WP)            // 1156
#define NPIX 1024
#define RSTR 34                // row stride in half2 units (paired layout)
#define NPR 18                 // paired rows per channel: pr holds rows (pr, pr+16)
#define CSTR (NPR*RSTR)        // 612 half2 per channel
#define GUARD 4                // guard half2 slots at front
#define TOT_H2 (GUARD + CIN*CSTR)   // 39,172 half2 = 156,688 B

// One block per (b,o), 512 threads, 2 px/thread (rows h0, h0+16).
// Paired-row f16 layout: s_img[GUARD + c*612 + pr*34 + col] is a half2
// holding padded rows (pr, pr+16) at physical col = padded col - 1.
// One ds_read_b32 per tap fetches BOTH of a thread's pixels; kw-1+w = -1
// underflows into the previous slot's zeroed col-33 (or the guard).
__global__ __launch_bounds__(512, 1) void reconv_pair(
    const float* __restrict__ images,
    const int* __restrict__ tap_idx, const float* __restrict__ tap_w,
    const int* __restrict__ bias_index, const float* __restrict__ bias_value,
    float* __restrict__ out)
{
    __shared__ unsigned int s_img[TOT_H2];   // half2 per slot
    __shared__ int2 s_tap[LMAX];             // .x = byte offset, .y = weight bits

    const int bo = blockIdx.x;
    const int b = bo >> 6;                   // / OC
    const int o = bo & (OC - 1);
    const int t = threadIdx.x;

    // --- Zero: guard + physical cols 32,33 of every (c,pr) ---
    if (t < GUARD / 2) ((unsigned long long*)s_img)[t] = 0ull;
    for (int i = t; i < CIN * NPR; i += 512) {
        int c = i / NPR;
        int pr = i - c * NPR;
        int e = GUARD + c * CSTR + pr * RSTR + 32;      // e even -> 8B aligned
        *(unsigned long long*)&s_img[e] = 0ull;
    }

    // --- Tap prep: idx -> packed byte offset + weight ---
    if (t < LMAX) {
        int idx = tap_idx[o * LMAX + t];
        int c = idx / HPW;
        int rem = idx - c * HPW;
        int kh = rem / WP;
        int kw = rem - kh * WP;
        int2 v;
        v.x = (GUARD + c * CSTR + kh * RSTR + kw - 1) * 4;
        v.y = __float_as_int(tap_w[o * LMAX + t]);
        s_tap[t] = v;
    }

    // --- Bias (general scatter-add semantics, uniform scalar work) ---
    float bias = 0.f;
    for (int i = 0; i < OC; ++i)
        bias += (bias_index[i] == o) ? bias_value[i] : 0.f;

    // --- Stage interior: image rows (ir, ir+16) packed as half2 ---
    // pr = ir+1 for ir in 0..15 -> lo = padded row ir+1 = img row ir,
    //                              hi = padded row ir+17 = img row ir+16.
    const float4* img4 = (const float4*)images + (size_t)b * (CIN * 32 * 32 / 4);
    const int q = t & 7;                     // float4 index within a 32-col row
    const int g = t >> 3;                    // 0..63
    #pragma unroll 4
    for (int i = 0; i < 16; ++i) {
        int rowid = i * 64 + g;              // 0..1023
        int c = rowid >> 4;
        int ir = rowid & 15;
        float4 a = img4[c * 256 + ir * 8 + q];
        float4 d = img4[c * 256 + (ir + 16) * 8 + q];
        unsigned int u0 = ((unsigned)__half_as_ushort(__float2half(d.x)) << 16) | __half_as_ushort(__float2half(a.x));
        unsigned int u1 = ((unsigned)__half_as_ushort(__float2half(d.y)) << 16) | __half_as_ushort(__float2half(a.y));
        unsigned int u2 = ((unsigned)__half_as_ushort(__float2half(d.z)) << 16) | __half_as_ushort(__float2half(a.z));
        unsigned int u3 = ((unsigned)__half_as_ushort(__float2half(d.w)) << 16) | __half_as_ushort(__float2half(a.w));
        int e = GUARD + c * CSTR + (ir + 1) * RSTR + 4 * q;   // e even -> 8B aligned
        *(unsigned long long*)&s_img[e]     = ((unsigned long long)u1 << 32) | u0;
        *(unsigned long long*)&s_img[e + 2] = ((unsigned long long)u3 << 32) | u2;
    }
    // Specials: pr=0 = {pad0, img row 15}; pr=17 = {img row 16, pad33}.
    for (int i = t; i < CIN * 8 * 2; i += 512) {     // 1024 tasks, 2/thread
        int c = i >> 4;
        int r2 = i & 15;
        int which = r2 >> 3;                 // 0 -> pr=0, 1 -> pr=17
        int qq = r2 & 7;
        float4 v = img4[c * 256 + (which ? 16 : 15) * 8 + qq];
        unsigned int u0, u1, u2, u3;
        if (which == 0) {                    // lo = 0 (padded row 0), hi = img15
            u0 = (unsigned)__half_as_ushort(__float2half(v.x)) << 16;
            u1 = (unsigned)__half_as_ushort(__float2half(v.y)) << 16;
            u2 = (unsigned)__half_as_ushort(__float2half(v.z)) << 16;
            u3 = (unsigned)__half_as_ushort(__float2half(v.w)) << 16;
        } else {                             // lo = img16, hi = 0 (padded row 33)
            u0 = __half_as_ushort(__float2half(v.x));
            u1 = __half_as_ushort(__float2half(v.y));
            u2 = __half_as_ushort(__float2half(v.z));
            u3 = __half_as_ushort(__float2half(v.w));
        }
        int e = GUARD + c * CSTR + (which ? 17 : 0) * RSTR + 4 * qq;
        *(unsigned long long*)&s_img[e]     = ((unsigned long long)u1 << 32) | u0;
        *(unsigned long long*)&s_img[e + 2] = ((unsigned long long)u3 << 32) | u2;
    }

    __syncthreads();

    // --- Gather: 2 DS ops per tap (tap b64 broadcast + data b32) ---
    const int w = t & 31;
    const int h0 = t >> 5;                   // 0..15
    const int pxb = (h0 * RSTR + w) * 4;     // thread's byte addend
    const char* sbase = (const char*)s_img;
    float a0 = 0.f, a1 = 0.f;
    #pragma unroll 8
    for (int l = 0; l < LMAX; ++l) {
        int2 tp = s_tap[l];                  // ds_read_b64, uniform broadcast
        __half2 hv = *(const __half2*)(sbase + (tp.x + pxb));
        float wgt = __int_as_float(tp.y);
        a0 = fmaf(wgt, __low2float(hv), a0);   // v_fma_mix_f32
        a1 = fmaf(wgt, __high2float(hv), a1);
    }

    float* op = out + (size_t)bo * NPIX;
    op[h0 * 32 + w] = a0 + bias;
    op[(h0 + 16) * 32 + w] = a1 + bias;
}

extern "C" void kernel_launch(void* const* d_in, const int* in_sizes, int n_in,
                              void* d_out, int out_size, void* d_ws, size_t ws_size,
                              hipStream_t stream) {
    const float* images     = (const float*)d_in[0];
    const int*   tap_idx    = (const int*)d_in[1];
    const float* tap_w      = (const float*)d_in[2];
    const int*   bias_index = (const int*)d_in[3];
    const float* bias_value = (const float*)d_in[4];
    float* out = (float*)d_out;

    reconv_pair<<<B * OC, 512, 0, stream>>>(images, tap_idx, tap_w,
                                            bias_index, bias_value, out);
}